// Round 6
// baseline (419.231 us; speedup 1.0000x reference)
//
#include <hip/hip_runtime.h>
#include <hip/hip_cooperative_groups.h>

namespace cg = cooperative_groups;

static constexpr int DIN = 512;
static constexpr int DOUT = 256;
static constexpr int CAP = 128;  // max in-degree (Poisson(32): P(any>128) ~ 1e-17)

typedef __attribute__((ext_vector_type(8))) short short8;
typedef __attribute__((ext_vector_type(4))) float f32x4;

__device__ inline unsigned short f2bf(float f) {
  unsigned int b = __float_as_uint(f);
  unsigned int r = (b + 0x7fffu + ((b >> 16) & 1u)) >> 16;
  return (unsigned short)r;
}
__device__ inline float bf_lo(unsigned int packed) { return __uint_as_float(packed << 16); }
__device__ inline float bf_hi(unsigned int packed) { return __uint_as_float(packed & 0xffff0000u); }

__device__ inline short8 cvt8(const float4 a, const float4 b) {
  short8 o;
  o[0] = (short)f2bf(a.x); o[1] = (short)f2bf(a.y);
  o[2] = (short)f2bf(a.z); o[3] = (short)f2bf(a.w);
  o[4] = (short)f2bf(b.x); o[5] = (short)f2bf(b.y);
  o[6] = (short)f2bf(b.z); o[7] = (short)f2bf(b.w);
  return o;
}

struct Params {
  const float* x;
  const int* ei;
  const float* ew;
  const float* W;
  float* out;
  unsigned short* h1b;
  unsigned short* wbb;
  float* deg;    // deg[n] ++ cursor[n] contiguous (zeroed as 2n words)
  int* cursor;
  uint2* bucket;
  int n, E;
};

// ---- phase 0: zero deg/cursor; W -> bf16 ----
__device__ inline void dev_init_wcvt(const Params& p) {
  const int gid = blockIdx.x * 256 + threadIdx.x;
  const int stride = gridDim.x * 256;
  int* dz = (int*)p.deg;  // covers deg[n] + cursor[n]
  for (int i = gid; i < 2 * p.n; i += stride) dz[i] = 0;
  const int wgroups = DOUT * DIN / 8;
  for (int i = gid; i < wgroups; i += stride) {
    const float4* src = (const float4*)(p.W + (size_t)i * 8);
    float4 a = src[0], b = src[1];
    *(short8*)(p.wbb + (size_t)i * 8) = cvt8(a, b);
  }
}

// ---- phase 1a: edges: deg[src] += w; bucket[dst] append (src,w) ----
__device__ inline void dev_edges(const Params& p) {
  const int stride = gridDim.x * 256;
  for (int e = blockIdx.x * 256 + threadIdx.x; e < p.E; e += stride) {
    int srcv = p.ei[e];
    int dstv = p.ei[p.E + e];
    float w = p.ew[e];
    atomicAdd(&p.deg[srcv], w);
    int pos = atomicAdd(&p.cursor[dstv], 1);
    if (pos < CAP) {
      uint2 v;
      v.x = (unsigned)srcv;
      v.y = __float_as_uint(w);
      p.bucket[(size_t)dstv * CAP + pos] = v;
    }
  }
}

// ---- phase 1b: GEMM mainloop (no deg dependency). One M16xN128 tile/block.
__device__ inline void dev_gemm_main(const Params& p, f32x4 acc[2]) {
  const int lane = threadIdx.x & 63;
  const int wv = threadIdx.x >> 6;
  const int bm = (blockIdx.x >> 1) * 16;
  const int colb = (blockIdx.x & 1) * 128 + wv * 32;
  const int r = lane & 15;
  const int kg = lane >> 4;
  const float* arow = p.x + (size_t)(bm + r) * DIN + kg * 8;
  const unsigned short* brow = p.wbb + (size_t)(colb + r) * DIN + kg * 8;
#pragma unroll
  for (int k0 = 0; k0 < DIN; k0 += 32) {
    float4 a0 = *(const float4*)(arow + k0);
    float4 a1 = *(const float4*)(arow + k0 + 4);
    short8 av = cvt8(a0, a1);
    short8 b0 = *(const short8*)(brow + k0);
    short8 b1 = *(const short8*)(brow + (size_t)16 * DIN + k0);
    acc[0] = __builtin_amdgcn_mfma_f32_16x16x32_bf16(av, b0, acc[0], 0, 0, 0);
    acc[1] = __builtin_amdgcn_mfma_f32_16x16x32_bf16(av, b1, acc[1], 0, 0, 0);
  }
}

// ---- phase 2: GEMM epilogue: h1b = bf16(rsqrt(1+deg[row]) * acc) ----
__device__ inline void dev_gemm_epi(const Params& p, f32x4 acc[2]) {
  const int lane = threadIdx.x & 63;
  const int wv = threadIdx.x >> 6;
  const int bm = (blockIdx.x >> 1) * 16;
  const int colb = (blockIdx.x & 1) * 128 + wv * 32;
  const int r = lane & 15;
  const int kg = lane >> 4;
#pragma unroll
  for (int i = 0; i < 4; ++i) {
    int row = bm + kg * 4 + i;
    float sr = __frsqrt_rn(1.0f + p.deg[row]);
    p.h1b[(size_t)row * DOUT + colb + r] = f2bf(sr * acc[0][i]);
    p.h1b[(size_t)row * DOUT + colb + 16 + r] = f2bf(sr * acc[1][i]);
  }
}

// ---- gather chunk: up to 64 edges held in (sv,wl) across the wave ----
__device__ inline void gather_chunk(float acc[8], int sv, float wl, int c,
                                    const unsigned short* h1b, int cl, int half) {
  const int npair = ((c + 15) >> 4) << 3;  // pad to mult of 16 edges; pads are src=0,w=0
  for (int j = 0; j < npair; j += 8) {
    uint4 rbuf[8];
#pragma unroll
    for (int u = 0; u < 8; ++u) {
      int src = __shfl(sv, 2 * (j + u) + half);
      rbuf[u] = *(const uint4*)(h1b + (size_t)src * DOUT + cl * 8);
    }
#pragma unroll
    for (int u = 0; u < 8; ++u) {
      float w = __shfl(wl, 2 * (j + u) + half);
      acc[0] = fmaf(w, bf_lo(rbuf[u].x), acc[0]);
      acc[1] = fmaf(w, bf_hi(rbuf[u].x), acc[1]);
      acc[2] = fmaf(w, bf_lo(rbuf[u].y), acc[2]);
      acc[3] = fmaf(w, bf_hi(rbuf[u].y), acc[3]);
      acc[4] = fmaf(w, bf_lo(rbuf[u].z), acc[4]);
      acc[5] = fmaf(w, bf_hi(rbuf[u].z), acc[5]);
      acc[6] = fmaf(w, bf_lo(rbuf[u].w), acc[6]);
      acc[7] = fmaf(w, bf_hi(rbuf[u].w), acc[7]);
    }
  }
}

// ---- phase 3: gather: out[d] = s[d]*(h1[d] + sum w*h1[src]) ; 2 dst/wave ----
__device__ inline void dev_gather(const Params& p) {
  const int lane = threadIdx.x & 63;
  const int wv = threadIdx.x >> 6;
  const int cl = lane & 31;
  const int half = lane >> 5;
  const int wid = blockIdx.x * 4 + wv;
  const int nw = gridDim.x * 4;
  for (int d = wid; d < p.n; d += nw) {
    const int cnt = min(p.cursor[d], CAP);
    const uint4 selfv = *(const uint4*)(p.h1b + (size_t)d * DOUT + cl * 8);
    const float sd = __frsqrt_rn(1.0f + p.deg[d]);
    uint2 ev0; ev0.x = 0u; ev0.y = 0u;
    uint2 ev1; ev1.x = 0u; ev1.y = 0u;
    if (lane < cnt) ev0 = p.bucket[(size_t)d * CAP + lane];
    if (64 + lane < cnt) ev1 = p.bucket[(size_t)d * CAP + 64 + lane];

    float acc[8] = {};
    gather_chunk(acc, (int)ev0.x, __uint_as_float(ev0.y), min(cnt, 64), p.h1b, cl, half);
    if (cnt > 64)
      gather_chunk(acc, (int)ev1.x, __uint_as_float(ev1.y), cnt - 64, p.h1b, cl, half);

#pragma unroll
    for (int k = 0; k < 8; ++k) acc[k] += __shfl_xor(acc[k], 32);

    if (half == 0) {
      float4 o0v, o1v;
      o0v.x = sd * (bf_lo(selfv.x) + acc[0]);
      o0v.y = sd * (bf_hi(selfv.x) + acc[1]);
      o0v.z = sd * (bf_lo(selfv.y) + acc[2]);
      o0v.w = sd * (bf_hi(selfv.y) + acc[3]);
      o1v.x = sd * (bf_lo(selfv.z) + acc[4]);
      o1v.y = sd * (bf_hi(selfv.z) + acc[5]);
      o1v.z = sd * (bf_lo(selfv.w) + acc[6]);
      o1v.w = sd * (bf_hi(selfv.w) + acc[7]);
      float* op = p.out + (size_t)d * DOUT + cl * 8;
      *(float4*)op = o0v;
      *(float4*)(op + 4) = o1v;
    }
  }
}

// ---- fused cooperative kernel ----
__global__ __launch_bounds__(256, 4) void k_fused(Params p) {
  cg::grid_group g = cg::this_grid();
  dev_init_wcvt(p);
  g.sync();
  dev_edges(p);               // atomic latency overlaps with...
  f32x4 acc[2] = {};
  dev_gemm_main(p, acc);      // ...the MFMA mainloop (no deg/bucket dependency)
  g.sync();
  dev_gemm_epi(p, acc);
  g.sync();
  dev_gather(p);
}

// ---- non-cooperative fallback path ----
__global__ __launch_bounds__(256) void k_p0(Params p) { dev_init_wcvt(p); }
__global__ __launch_bounds__(256) void k_p1(Params p) { dev_edges(p); }
__global__ __launch_bounds__(256) void k_p2(Params p) {
  f32x4 acc[2] = {};
  dev_gemm_main(p, acc);
  dev_gemm_epi(p, acc);
}
__global__ __launch_bounds__(256, 4) void k_p3(Params p) { dev_gather(p); }

extern "C" void kernel_launch(void* const* d_in, const int* in_sizes, int n_in,
                              void* d_out, int out_size, void* d_ws, size_t ws_size,
                              hipStream_t stream) {
  Params p;
  p.x = (const float*)d_in[0];
  p.ei = (const int*)d_in[1];  // [2, E]: row0 = src, row1 = dst
  p.ew = (const float*)d_in[2];
  p.W = (const float*)d_in[3];
  p.out = (float*)d_out;
  p.n = in_sizes[0] / DIN;  // 8192
  p.E = in_sizes[2];        // 262144

  char* q = (char*)d_ws;
  auto alloc = [&](size_t bytes) {
    char* r = q;
    q += (bytes + 255) & ~(size_t)255;
    return r;
  };
  p.h1b = (unsigned short*)alloc((size_t)p.n * DOUT * 2);
  p.wbb = (unsigned short*)alloc((size_t)DOUT * DIN * 2);
  p.deg = (float*)alloc((size_t)p.n * 4 * 2);  // deg[n] ++ cursor[n]
  p.cursor = (int*)(p.deg + p.n);
  p.bucket = (uint2*)alloc((size_t)p.n * CAP * 8);

  dim3 grid((p.n / 16) * 2);  // 1024 blocks = one GEMM tile each; 4 blocks/CU
  dim3 block(256);
  void* args[] = {&p};
  hipError_t err =
      hipLaunchCooperativeKernel((const void*)k_fused, grid, block, args, 0, stream);
  if (err != hipSuccess) {
    k_p0<<<grid, block, 0, stream>>>(p);
    k_p1<<<grid, block, 0, stream>>>(p);
    k_p2<<<grid, block, 0, stream>>>(p);
    k_p3<<<grid, block, 0, stream>>>(p);
  }
}